// Round 7
// baseline (198.222 us; speedup 1.0000x reference)
//
#include <hip/hip_runtime.h>

#define BSZ 64
#define QN  1024
#define TN  128
#define NCL 20
#define INFV 1e30f

typedef float f32x2 __attribute__((ext_vector_type(2)));
typedef float f32x4 __attribute__((ext_vector_type(4)));

template<int CTRL>
__device__ __forceinline__ float dpp_min(float x) {
    int r = __builtin_amdgcn_mov_dpp(__float_as_int(x), CTRL, 0xF, 0xF, false);
    return fminf(x, __int_as_float(r));
}
__device__ __forceinline__ float min3f(float a, float b, float c) {
    float d;
    asm("v_min3_f32 %0, %1, %2, %3" : "=v"(d) : "v"(a), "v"(b), "v"(c));
    return d;
}
__device__ __forceinline__ float swap32_min(float x) {
    float a = x, b = x;
    asm volatile("v_permlane32_swap_b32 %0, %1" : "+v"(a), "+v"(b));
    return min3f(x, a, b);
}
__device__ __forceinline__ float swap16_min(float x) {
    float a = x, b = x;
    asm volatile("v_permlane16_swap_b32 %0, %1" : "+v"(a), "+v"(b));
    return min3f(x, a, b);
}
__device__ __forceinline__ int rdl(int v, int l) {
    return __builtin_amdgcn_readlane(v, l);
}
__device__ __forceinline__ float rdlf(float v, int l) {
    return __int_as_float(__builtin_amdgcn_readlane(__float_as_int(v), l));
}

// 256 threads = 4 waves per batch. Wave w owns columns [w*256, w*256+256),
// lane owns 4 columns c = w*256 + lane*4 + s. Cross-wave argmin via a
// seq-tagged SPIN mailbox (parity double-buffered b64 slots) — NO barrier
// on the per-iteration path. Row-side state replicated per wave in registers.
__global__ __launch_bounds__(256) void lsa_fused_kernel(
    const float* __restrict__ pred_logits, // (B,Q,NC)
    const float* __restrict__ pred_coords, // (B,Q,2)
    const int*   __restrict__ tgt_labels,  // (B,T)
    const float* __restrict__ tgt_joints,  // (B,T,2)
    int*         __restrict__ out)         // pred_idx (B,T) ++ tgt_idx (B,T)
{
    const int b    = blockIdx.x;
    const int tid  = threadIdx.x;
    const int w    = tid >> 6;
    const int lane = tid & 63;

    __shared__ __align__(16) float    probP[NCL * QN]; // 80 KB, [class][q]
    __shared__ __align__(16) float    cmS[QN];         // frozen spc dump
    __shared__ uint32_t pthBW[QN / 4];                 // path bytes, 1/col
    __shared__ uint8_t  labsB[TN];
    __shared__ int      c4rS[TN];
    __shared__ __align__(16) unsigned long long commLL[8]; // [par][w] slots

    // ---- stage softmax(logits) into LDS, same op order as before ----
    {
        const float* lg = pred_logits + (size_t)b * QN * NCL;
#pragma unroll
        for (int k = 0; k < 4; ++k) {
            int q = tid * 4 + k;
            const f32x4* rp = (const f32x4*)(lg + (size_t)q * NCL); // 80B rows
            float x[NCL];
            *(f32x4*)&x[0]  = rp[0];
            *(f32x4*)&x[4]  = rp[1];
            *(f32x4*)&x[8]  = rp[2];
            *(f32x4*)&x[12] = rp[3];
            *(f32x4*)&x[16] = rp[4];
            float mx = x[0];
#pragma unroll
            for (int c = 1; c < NCL; ++c) mx = fmaxf(mx, x[c]);
            float e[NCL];
            float ssum = 0.f;
#pragma unroll
            for (int c = 0; c < NCL; ++c) { e[c] = expf(x[c] - mx); ssum += e[c]; }
#pragma unroll
            for (int c = 0; c < NCL; ++c) probP[c * QN + q] = e[c] / ssum;
        }
    }
    if (tid < TN) labsB[tid] = (uint8_t)(tgt_labels[(size_t)b * TN + tid] & 0xFF);
    if (tid < 8)  commLL[tid] = 0ull;   // seq 0 never used (gseq starts at 1)

    // ---- per-lane column state (c = c0 + s, s in 0..3) ----
    const int c0 = w * 256 + lane * 4;
    const float2* pcg = (const float2*)pred_coords + (size_t)b * QN;
    f32x2 pxp[2], pyp[2], vvp[2];
#pragma unroll
    for (int s = 0; s < 4; ++s) {
        float2 P = pcg[c0 + s];
        pxp[s >> 1][s & 1] = P.x;
        pyp[s >> 1][s & 1] = P.y;
        vvp[s >> 1][s & 1] = 0.f;
    }
    int rc[4];   // row4col for owned cols (0xFF = unassigned)
    int pk[4];   // col | rc<<10 | lab<<18 (bits 0..22; seq uses 24+)
#pragma unroll
    for (int s = 0; s < 4; ++s) { rc[s] = 0xFF; pk[s] = (c0 + s) | (0xFF << 10); }

    // ---- row-side state, replicated identically in every wave ----
    const int*    labsg = tgt_labels + (size_t)b * TN;
    const float2* tjg   = (const float2*)tgt_joints + (size_t)b * TN;
    int    labAB = (labsg[lane] & 0xFF) | ((labsg[lane + 64] & 0xFF) << 8);
    float2 tjA = tjg[lane], tjB = tjg[lane + 64];
    float  u0 = 0.f, u1 = 0.f;
    int    c4rA = -1, c4rB = -1;
    __syncthreads();

    unsigned gseq = 1;                 // global iteration sequence (mod 256 tag)
    f32x4 pr4;
    float tx, ty, u_i;
    {   // prologue for scan 0 (row 0)
        int labI = rdl(labAB, 0) & 0xFF;
        pr4 = *(const f32x4*)&probP[labI * QN + c0];
        tx = rdlf(tjA.x, 0); ty = rdlf(tjA.y, 0); u_i = rdlf(u0, 0);
    }

    for (int cur = 0; cur < TN; ++cur) {
        float sp[4];
        int   pth[4];
        unsigned scMask = 0;
#pragma unroll
        for (int s = 0; s < 4; ++s) { sp[s] = INFV; pth[s] = 0; }

        float minVal = 0.f;
        int   i_s = cur, sinkJ = -1, iters = 0;

        while (true) {
            // ---- relax 4 owned columns (reference float op order) ----
            f32x2 tx2 = {tx, tx}, ty2 = {ty, ty};
            f32x2 mv2 = {minVal, minVal}, ui2 = {u_i, u_i};
            float mval[4];
#pragma unroll
            for (int p = 0; p < 2; ++p) {
                f32x2 pr; pr[0] = pr4[p * 2]; pr[1] = pr4[p * 2 + 1];
                f32x2 dx = pxp[p] - tx2;
                f32x2 dy = pyp[p] - ty2;
                f32x2 cb = __builtin_elementwise_abs(dx) + __builtin_elementwise_abs(dy);
                f32x2 cost = cb - pr;                      // bbox + (-prob)
                f32x2 r2 = ((mv2 + cost) - ui2) - vvp[p];
#pragma unroll
                for (int e = 0; e < 2; ++e) {
                    const int s = p * 2 + e;
                    bool unm = ((scMask >> s) & 1u) == 0u;
                    float r = r2[e];
                    bool upd = unm && (r < sp[s]);
                    sp[s]   = upd ? r   : sp[s];
                    pth[s]  = upd ? i_s : pth[s];
                    mval[s] = unm ? sp[s] : INFV;
                }
            }
            // ---- lane-local argmin (4 slots, lowest slot on ties) ----
            bool t1 = mval[1] < mval[0];
            float vA = t1 ? mval[1] : mval[0]; int kA = t1 ? pk[1] : pk[0];
            bool t2 = mval[3] < mval[2];
            float vB = t2 ? mval[3] : mval[2]; int kB = t2 ? pk[3] : pk[2];
            bool t3 = vB < vA;
            float lmin = t3 ? vB : vA;  int lpk = t3 ? kB : kA;

            // ---- wave-local VALU min + first-lane candidate ----
            float g = swap32_min(lmin);
            g = swap16_min(g);
            g = dpp_min<0x128>(g); g = dpp_min<0x124>(g);
            g = dpp_min<0x122>(g); g = dpp_min<0x121>(g);
            float gw = __int_as_float(
                __builtin_amdgcn_readfirstlane(__float_as_int(g)));
            unsigned long long mk = __ballot(lmin == gw);
            int L = __ffsll(mk) - 1;
            int wpk = rdl(lpk, L);

            // ---- publish seq-tagged candidate; spin until all 4 current ----
            const unsigned tag = gseq & 0xFFu;
            volatile unsigned long long* mb =
                (volatile unsigned long long*)&commLL[(gseq & 1u) * 4];
            {
                unsigned hi = (unsigned)wpk | (tag << 24);
                unsigned long long pack =
                    ((unsigned long long)hi << 32) | (unsigned)__float_as_int(gw);
                if (lane == 0) mb[w] = pack;
            }
            unsigned long long s0, s1, s2, s3;
            int guardp = 0;
            for (;;) {
                s0 = mb[0]; s1 = mb[1]; s2 = mb[2]; s3 = mb[3];
                bool ok = ((unsigned)(s0 >> 56) == tag) &
                          ((unsigned)(s1 >> 56) == tag) &
                          ((unsigned)(s2 >> 56) == tag) &
                          ((unsigned)(s3 >> 56) == tag);
                if (ok) break;
                if (++guardp > (1 << 18)) break;   // hang guard
            }
            ++gseq;

            // ---- combine 4 candidates (left-priority ties) ----
            float v0 = __int_as_float((int)(unsigned)s0);
            float v1 = __int_as_float((int)(unsigned)s1);
            float v2 = __int_as_float((int)(unsigned)s2);
            float v3 = __int_as_float((int)(unsigned)s3);
            int k0 = (int)(unsigned)(s0 >> 32), k1 = (int)(unsigned)(s1 >> 32);
            int k2 = (int)(unsigned)(s2 >> 32), k3 = (int)(unsigned)(s3 >> 32);
            bool b1 = v1 < v0; float vX = b1 ? v1 : v0; int kX = b1 ? k1 : k0;
            bool b2 = v3 < v2; float vY = b2 ? v3 : v2; int kY = b2 ? k3 : k2;
            bool b3 = vY < vX; float gv = b3 ? vY : vX; int gpk = b3 ? kY : kX;
            minVal = gv;

            const int j     = gpk & 1023;
            const int rbyte = (gpk >> 10) & 0xFF;
            sinkJ = j;
            if (w == (j >> 8) && lane == ((j >> 2) & 63))
                scMask |= 1u << (j & 3);
            if (rbyte == 0xFF) break;          // unassigned column -> sink
            if (++iters > QN + 2) break;       // safety guard

            // ---- next row: issue prob load, then broadcasts ----
            const int labI = (gpk >> 18) & 0x1F;
            pr4 = *(const f32x4*)&probP[labI * QN + c0];
            i_s = rbyte;
            bool hi = i_s >= 64; int l6 = i_s & 63;
            tx  = rdlf(hi ? tjB.x : tjA.x, l6);
            ty  = rdlf(hi ? tjB.y : tjA.y, l6);
            u_i = rdlf(hi ? u1 : u0, l6);
        }

        // ---- dump frozen spc + path bytes ----
        f32x4 dmp;
#pragma unroll
        for (int s = 0; s < 4; ++s)
            dmp[s] = ((scMask >> s) & 1u) ? sp[s] : INFV;
        *(f32x4*)&cmS[c0] = dmp;
        pthBW[(unsigned)c0 >> 2] =
            (uint32_t)(pth[0] & 0xFF)        | ((uint32_t)(pth[1] & 0xFF) << 8) |
            ((uint32_t)(pth[2] & 0xFF) << 16) | ((uint32_t)(pth[3] & 0xFF) << 24);
        const int c4A_old = c4rA, c4B_old = c4rB;
        __syncthreads();

        // gathers for u update (pre-augment col4row snapshot)
        float wvA = cmS[c4A_old < 0 ? 0 : c4A_old];
        float wvB = cmS[c4B_old < 0 ? 0 : c4B_old];

        // ---- augment walk (replicated, uniform) ----
        {
            const uint8_t* pthB = (const uint8_t*)pthBW;
            int jx = sinkJ;
            for (int it = 0; it <= TN; ++it) {
                int ii = pthB[jx];
                bool me = (w == (jx >> 8)) && (lane == ((jx >> 2) & 63));
                int sl = jx & 3;
#pragma unroll
                for (int s = 0; s < 4; ++s)
                    rc[s] = (me && s == sl) ? ii : rc[s];
                bool hi2 = ii >= 64; int cown = ii & 63;
                int nj = rdl(hi2 ? c4rB : c4rA, cown);
                if (lane == cown) { if (hi2) c4rB = jx; else c4rA = jx; }
                jx = nj;
                if (ii == cur) break;
            }
        }

        // ---- v update (own columns) + pk rebuild ----
#pragma unroll
        for (int s = 0; s < 4; ++s) {
            if ((scMask >> s) & 1u)
                vvp[s >> 1][s & 1] -= (minVal - sp[s]);
        }
#pragma unroll
        for (int s = 0; s < 4; ++s) {
            int lr = labsB[rc[s] & 127];
            pk[s] = (c0 + s) | (rc[s] << 10) | (lr << 18);
        }

        // ---- u update (reference semantics; replicated) ----
        if (lane == (cur & 63)) {
            if (cur >= 64) u1 += minVal; else u0 += minVal;
        }
        if (lane != cur && c4A_old >= 0 && wvA < 5e29f) u0 += minVal - wvA;
        {
            int rr = lane + 64;
            if (rr != cur && c4B_old >= 0 && wvB < 5e29f) u1 += minVal - wvB;
        }

        // ---- prologue for next scan ----
        {
            int curN = (cur < TN - 1) ? cur + 1 : TN - 1;
            int lw = rdl(labAB, curN & 63);
            int labI = (lw >> ((curN >> 6) * 8)) & 0xFF;
            pr4 = *(const f32x4*)&probP[labI * QN + c0];
            bool hi = curN >= 64; int l6 = curN & 63;
            tx  = rdlf(hi ? tjB.x : tjA.x, l6);
            ty  = rdlf(hi ? tjB.y : tjA.y, l6);
            u_i = rdlf(hi ? u1 : u0, l6);
        }
    }

    // ---- outputs: rank = #smaller (col4row values distinct) ----
    if (w == 0) { c4rS[lane] = c4rA; c4rS[lane + 64] = c4rB; }
    __syncthreads();
    if (tid < TN) {
        int t = tid;
        int q = c4rS[t];
        int rank = 0;
        for (int s = 0; s < TN; ++s) rank += (c4rS[s] < q) ? 1 : 0;
        out[(size_t)b * TN + rank] = q;            // pred_idx
        out[(size_t)(BSZ + b) * TN + rank] = t;    // tgt_idx
    }
}

extern "C" void kernel_launch(void* const* d_in, const int* in_sizes, int n_in,
                              void* d_out, int out_size, void* d_ws, size_t ws_size,
                              hipStream_t stream) {
    const float* pred_logits = (const float*)d_in[0]; // (B,Q,NC)
    const float* pred_coords = (const float*)d_in[1]; // (B,Q,2)
    const int*   tgt_labels  = (const int*)d_in[2];   // (B,T)
    const float* tgt_joints  = (const float*)d_in[3]; // (B,T,2)

    lsa_fused_kernel<<<BSZ, 256, 0, stream>>>(pred_logits, pred_coords,
                                              tgt_labels, tgt_joints,
                                              (int*)d_out);
}

// Round 11
// 176.007 us; speedup vs baseline: 1.1262x; 1.1262x over previous
//
#include <hip/hip_runtime.h>

#define BSZ 64
#define QN  1024
#define TN  128
#define NCL 20
#define INFV 1e30f

typedef float f32x2 __attribute__((ext_vector_type(2)));
typedef float f32x4 __attribute__((ext_vector_type(4)));

template<int CTRL>
__device__ __forceinline__ float dpp_min(float x) {
    int r = __builtin_amdgcn_mov_dpp(__float_as_int(x), CTRL, 0xF, 0xF, false);
    return fminf(x, __int_as_float(r));
}
__device__ __forceinline__ float min3f(float a, float b, float c) {
    float d;
    asm("v_min3_f32 %0, %1, %2, %3" : "=v"(d) : "v"(a), "v"(b), "v"(c));
    return d;
}
__device__ __forceinline__ float swap32_min(float x) {
    float a = x, b = x;
    asm volatile("v_permlane32_swap_b32 %0, %1" : "+v"(a), "+v"(b));
    return min3f(x, a, b);
}
__device__ __forceinline__ float swap16_min(float x) {
    float a = x, b = x;
    asm volatile("v_permlane16_swap_b32 %0, %1" : "+v"(a), "+v"(b));
    return min3f(x, a, b);
}
__device__ __forceinline__ int rdl(int v, int l) {
    return __builtin_amdgcn_readlane(v, l);
}
__device__ __forceinline__ float rdlf(float v, int l) {
    return __int_as_float(__builtin_amdgcn_readlane(__float_as_int(v), l));
}

// 256 threads = 4 waves per batch. Wave w owns columns [w*256, w*256+256),
// lane owns 4 columns c = w*256 + lane*4 + s. Cross-wave argmin via an LDS
// mailbox (parity double-buffered), ONE barrier per Dijkstra iteration.
// Row-side state (u, tj, labels, col4row) replicated per wave in registers.
__global__ __launch_bounds__(256) void lsa_fused_kernel(
    const float* __restrict__ pred_logits, // (B,Q,NC)
    const float* __restrict__ pred_coords, // (B,Q,2)
    const int*   __restrict__ tgt_labels,  // (B,T)
    const float* __restrict__ tgt_joints,  // (B,T,2)
    int*         __restrict__ out)         // pred_idx (B,T) ++ tgt_idx (B,T)
{
    const int b    = blockIdx.x;
    const int tid  = threadIdx.x;
    const int w    = tid >> 6;
    const int lane = tid & 63;

    __shared__ __align__(16) float    probP[NCL * QN]; // 80 KB, [class][q]
    __shared__ __align__(16) float    cmS[QN];         // frozen spc dump
    __shared__ uint32_t pthBW[QN / 4];                 // path bytes, 1/col
    __shared__ uint8_t  labsB[TN];
    __shared__ int      c4rS[TN];
    __shared__ __align__(16) int comm[16];             // [par][w]: (valbits, pk)

    // ---- stage softmax(logits) into LDS, same op order as before ----
    {
        const float* lg = pred_logits + (size_t)b * QN * NCL;
#pragma unroll
        for (int k = 0; k < 4; ++k) {
            int q = tid * 4 + k;
            const f32x4* rp = (const f32x4*)(lg + (size_t)q * NCL); // 80B rows
            float x[NCL];
            *(f32x4*)&x[0]  = rp[0];
            *(f32x4*)&x[4]  = rp[1];
            *(f32x4*)&x[8]  = rp[2];
            *(f32x4*)&x[12] = rp[3];
            *(f32x4*)&x[16] = rp[4];
            float mx = x[0];
#pragma unroll
            for (int c = 1; c < NCL; ++c) mx = fmaxf(mx, x[c]);
            float e[NCL];
            float ssum = 0.f;
#pragma unroll
            for (int c = 0; c < NCL; ++c) { e[c] = expf(x[c] - mx); ssum += e[c]; }
#pragma unroll
            for (int c = 0; c < NCL; ++c) probP[c * QN + q] = e[c] / ssum;
        }
    }
    if (tid < TN) labsB[tid] = (uint8_t)(tgt_labels[(size_t)b * TN + tid] & 0xFF);

    // ---- per-lane column state (c = c0 + s, s in 0..3) ----
    const int c0 = w * 256 + lane * 4;
    const float2* pcg = (const float2*)pred_coords + (size_t)b * QN;
    f32x2 pxp[2], pyp[2], vvp[2];
#pragma unroll
    for (int s = 0; s < 4; ++s) {
        float2 P = pcg[c0 + s];
        pxp[s >> 1][s & 1] = P.x;
        pyp[s >> 1][s & 1] = P.y;
        vvp[s >> 1][s & 1] = 0.f;
    }
    int rc[4];   // row4col for owned cols (0xFF = unassigned)
    int pk[4];   // col | rc<<10 | lab<<18 (rebuilt per scan)
#pragma unroll
    for (int s = 0; s < 4; ++s) { rc[s] = 0xFF; pk[s] = (c0 + s) | (0xFF << 10); }

    // ---- row-side state, replicated identically in every wave ----
    const int*    labsg = tgt_labels + (size_t)b * TN;
    const float2* tjg   = (const float2*)tgt_joints + (size_t)b * TN;
    int    labAB = (labsg[lane] & 0xFF) | ((labsg[lane + 64] & 0xFF) << 8);
    float2 tjA = tjg[lane], tjB = tjg[lane + 64];
    float  u0 = 0.f, u1 = 0.f;
    int    c4rA = -1, c4rB = -1;
    __syncthreads();

    int par = 0;
    f32x4 pr4;
    float tx, ty, u_i;
    {   // prologue for scan 0 (row 0)
        int labI = rdl(labAB, 0) & 0xFF;
        pr4 = *(const f32x4*)&probP[labI * QN + c0];
        tx = rdlf(tjA.x, 0); ty = rdlf(tjA.y, 0); u_i = rdlf(u0, 0);
    }

    for (int cur = 0; cur < TN; ++cur) {
        float sp[4];
        int   pth[4];
        unsigned scMask = 0;
#pragma unroll
        for (int s = 0; s < 4; ++s) { sp[s] = INFV; pth[s] = 0; }

        float minVal = 0.f;
        int   i_s = cur, sinkJ = -1, iters = 0;

        while (true) {
            // ---- relax 4 owned columns (reference float op order) ----
            f32x2 tx2 = {tx, tx}, ty2 = {ty, ty};
            f32x2 mv2 = {minVal, minVal}, ui2 = {u_i, u_i};
            float mval[4];
#pragma unroll
            for (int p = 0; p < 2; ++p) {
                f32x2 pr; pr[0] = pr4[p * 2]; pr[1] = pr4[p * 2 + 1];
                f32x2 dx = pxp[p] - tx2;
                f32x2 dy = pyp[p] - ty2;
                f32x2 cb = __builtin_elementwise_abs(dx) + __builtin_elementwise_abs(dy);
                f32x2 cost = cb - pr;                      // bbox + (-prob)
                f32x2 r2 = ((mv2 + cost) - ui2) - vvp[p];
#pragma unroll
                for (int e = 0; e < 2; ++e) {
                    const int s = p * 2 + e;
                    bool unm = ((scMask >> s) & 1u) == 0u;
                    float r = r2[e];
                    bool upd = unm && (r < sp[s]);
                    sp[s]   = upd ? r   : sp[s];
                    pth[s]  = upd ? i_s : pth[s];
                    mval[s] = unm ? sp[s] : INFV;
                }
            }
            // ---- lane-local argmin (4 slots, lowest slot on ties) ----
            bool t1 = mval[1] < mval[0];
            float vA = t1 ? mval[1] : mval[0]; int kA = t1 ? pk[1] : pk[0];
            bool t2 = mval[3] < mval[2];
            float vB = t2 ? mval[3] : mval[2]; int kB = t2 ? pk[3] : pk[2];
            bool t3 = vB < vA;
            float lmin = t3 ? vB : vA;  int lpk = t3 ? kB : kA;

            // ---- wave-local VALU min + first-lane candidate ----
            float g = swap32_min(lmin);
            g = swap16_min(g);
            g = dpp_min<0x128>(g); g = dpp_min<0x124>(g);
            g = dpp_min<0x122>(g); g = dpp_min<0x121>(g);
            float gw = __int_as_float(
                __builtin_amdgcn_readfirstlane(__float_as_int(g)));
            unsigned long long mk = __ballot(lmin == gw);
            int L = __ffsll(mk) - 1;
            int wpk = rdl(lpk, L);

            // ---- publish wave candidate; combine 4 (left-priority ties) ----
            if (lane == 0)
                *(int2*)&comm[par * 8 + w * 2] = make_int2(__float_as_int(gw), wpk);
            __syncthreads();
            int4 ra = *(const int4*)&comm[par * 8 + 0];
            int4 rb = *(const int4*)&comm[par * 8 + 4];
            par ^= 1;
            float v0 = __int_as_float(ra.x), v1 = __int_as_float(ra.z);
            float v2 = __int_as_float(rb.x), v3 = __int_as_float(rb.z);
            bool s1 = v1 < v0; float vX = s1 ? v1 : v0; int kX = s1 ? ra.w : ra.y;
            bool s2 = v3 < v2; float vY = s2 ? v3 : v2; int kY = s2 ? rb.w : rb.y;
            bool s3 = vY < vX; float gv = s3 ? vY : vX; int gpk = s3 ? kY : kX;
            minVal = gv;

            const int j     = gpk & 1023;
            const int rbyte = (gpk >> 10) & 0xFF;
            sinkJ = j;
            if (w == (j >> 8) && lane == ((j >> 2) & 63))
                scMask |= 1u << (j & 3);
            if (rbyte == 0xFF) break;          // unassigned column -> sink
            if (++iters > QN + 2) break;       // safety guard

            // ---- next row: issue prob load, then broadcasts ----
            const int labI = gpk >> 18;
            pr4 = *(const f32x4*)&probP[labI * QN + c0];
            i_s = rbyte;
            bool hi = i_s >= 64; int l6 = i_s & 63;
            tx  = rdlf(hi ? tjB.x : tjA.x, l6);
            ty  = rdlf(hi ? tjB.y : tjA.y, l6);
            u_i = rdlf(hi ? u1 : u0, l6);
        }

        // ---- dump frozen spc + path bytes ----
        f32x4 dmp;
#pragma unroll
        for (int s = 0; s < 4; ++s)
            dmp[s] = ((scMask >> s) & 1u) ? sp[s] : INFV;
        *(f32x4*)&cmS[c0] = dmp;
        pthBW[(unsigned)c0 >> 2] =
            (uint32_t)(pth[0] & 0xFF)        | ((uint32_t)(pth[1] & 0xFF) << 8) |
            ((uint32_t)(pth[2] & 0xFF) << 16) | ((uint32_t)(pth[3] & 0xFF) << 24);
        const int c4A_old = c4rA, c4B_old = c4rB;
        __syncthreads();

        // gathers for u update (pre-augment col4row snapshot)
        float wvA = cmS[c4A_old < 0 ? 0 : c4A_old];
        float wvB = cmS[c4B_old < 0 ? 0 : c4B_old];

        // ---- augment walk (replicated, uniform) ----
        {
            const uint8_t* pthB = (const uint8_t*)pthBW;
            int jx = sinkJ;
            for (int it = 0; it <= TN; ++it) {
                int ii = pthB[jx];
                bool me = (w == (jx >> 8)) && (lane == ((jx >> 2) & 63));
                int sl = jx & 3;
#pragma unroll
                for (int s = 0; s < 4; ++s)
                    rc[s] = (me && s == sl) ? ii : rc[s];
                bool hi2 = ii >= 64; int cown = ii & 63;
                int nj = rdl(hi2 ? c4rB : c4rA, cown);
                if (lane == cown) { if (hi2) c4rB = jx; else c4rA = jx; }
                jx = nj;
                if (ii == cur) break;
            }
        }

        // ---- v update (own columns) + pk rebuild ----
#pragma unroll
        for (int s = 0; s < 4; ++s) {
            if ((scMask >> s) & 1u)
                vvp[s >> 1][s & 1] -= (minVal - sp[s]);
        }
#pragma unroll
        for (int s = 0; s < 4; ++s) {
            int lr = labsB[rc[s] & 127];
            pk[s] = (c0 + s) | (rc[s] << 10) | (lr << 18);
        }

        // ---- u update (reference semantics; replicated) ----
        if (lane == (cur & 63)) {
            if (cur >= 64) u1 += minVal; else u0 += minVal;
        }
        if (lane != cur && c4A_old >= 0 && wvA < 5e29f) u0 += minVal - wvA;
        {
            int rr = lane + 64;
            if (rr != cur && c4B_old >= 0 && wvB < 5e29f) u1 += minVal - wvB;
        }

        // ---- prologue for next scan ----
        {
            int curN = (cur < TN - 1) ? cur + 1 : TN - 1;
            int lw = rdl(labAB, curN & 63);
            int labI = (lw >> ((curN >> 6) * 8)) & 0xFF;
            pr4 = *(const f32x4*)&probP[labI * QN + c0];
            bool hi = curN >= 64; int l6 = curN & 63;
            tx  = rdlf(hi ? tjB.x : tjA.x, l6);
            ty  = rdlf(hi ? tjB.y : tjA.y, l6);
            u_i = rdlf(hi ? u1 : u0, l6);
        }
    }

    // ---- outputs: rank = #smaller (col4row values distinct) ----
    if (w == 0) { c4rS[lane] = c4rA; c4rS[lane + 64] = c4rB; }
    __syncthreads();
    if (tid < TN) {
        int t = tid;
        int q = c4rS[t];
        int rank = 0;
        for (int s = 0; s < TN; ++s) rank += (c4rS[s] < q) ? 1 : 0;
        out[(size_t)b * TN + rank] = q;            // pred_idx
        out[(size_t)(BSZ + b) * TN + rank] = t;    // tgt_idx
    }
}

extern "C" void kernel_launch(void* const* d_in, const int* in_sizes, int n_in,
                              void* d_out, int out_size, void* d_ws, size_t ws_size,
                              hipStream_t stream) {
    const float* pred_logits = (const float*)d_in[0]; // (B,Q,NC)
    const float* pred_coords = (const float*)d_in[1]; // (B,Q,2)
    const int*   tgt_labels  = (const int*)d_in[2];   // (B,T)
    const float* tgt_joints  = (const float*)d_in[3]; // (B,T,2)

    lsa_fused_kernel<<<BSZ, 256, 0, stream>>>(pred_logits, pred_coords,
                                              tgt_labels, tgt_joints,
                                              (int*)d_out);
}